// Round 2
// baseline (245.162 us; speedup 1.0000x reference)
//
#include <hip/hip_runtime.h>

#define Bq 64
#define Sq 256
#define Dq 768
#define CAPq 8
#define NTq 10
#define SCq 2048   // S*CAP

// ---------------- Kernel 1: sem[b,s,c,n] = x[b,s,:]·fc1_w[n,c,:] + b, squash over n,
// write u[b][n][s*8+c]  (u is [B][NT][S*CAP])
__global__ __launch_bounds__(256) void k1_sem(const float* __restrict__ x,
                                              const float* __restrict__ fc1w,
                                              const float* __restrict__ fc1b,
                                              float* __restrict__ u) {
    __shared__ float xs[64][33];
    __shared__ float ws[80][33];
    const int t = threadIdx.x;
    const int R0 = blockIdx.x * 64;           // global row = b*256 + s
    const int rp = t >> 3;                    // 0..31 -> rows 2rp, 2rp+1
    const int cc = t & 7;                     // capsule
    float acc0[NTq], acc1[NTq];
#pragma unroll
    for (int n = 0; n < NTq; ++n) { acc0[n] = 0.f; acc1[n] = 0.f; }

    for (int kc = 0; kc < Dq; kc += 32) {
#pragma unroll
        for (int i = 0; i < 2; ++i) {
            int lin = t + i * 256;            // 0..511
            int r = lin >> 3, k4 = (lin & 7) * 4;
            float4 v = *reinterpret_cast<const float4*>(&x[(size_t)(R0 + r) * Dq + kc + k4]);
            xs[r][k4] = v.x; xs[r][k4+1] = v.y; xs[r][k4+2] = v.z; xs[r][k4+3] = v.w;
        }
#pragma unroll
        for (int i = 0; i < 3; ++i) {
            int lin = t + i * 256;
            if (lin < 640) {                  // 80*32/4
                int o = lin >> 3, k4 = (lin & 7) * 4;
                float4 v = *reinterpret_cast<const float4*>(&fc1w[(size_t)o * Dq + kc + k4]);
                ws[o][k4] = v.x; ws[o][k4+1] = v.y; ws[o][k4+2] = v.z; ws[o][k4+3] = v.w;
            }
        }
        __syncthreads();
#pragma unroll
        for (int k = 0; k < 32; ++k) {
            float x0 = xs[2*rp][k], x1 = xs[2*rp+1][k];
#pragma unroll
            for (int n = 0; n < NTq; ++n) {
                float wv = ws[n*8 + cc][k];
                acc0[n] = fmaf(x0, wv, acc0[n]);
                acc1[n] = fmaf(x1, wv, acc1[n]);
            }
        }
        __syncthreads();
    }
    float sq0 = 0.f, sq1 = 0.f;
#pragma unroll
    for (int n = 0; n < NTq; ++n) {
        float bias = fc1b[n*8 + cc];
        acc0[n] += bias; acc1[n] += bias;
        sq0 = fmaf(acc0[n], acc0[n], sq0);
        sq1 = fmaf(acc1[n], acc1[n], sq1);
    }
    float sc0 = (sq0 / (1.f + sq0)) / sqrtf(sq0);
    float sc1 = (sq1 / (1.f + sq1)) / sqrtf(sq1);
    int row0 = R0 + 2*rp, row1 = row0 + 1;
    int b0 = row0 >> 8, s0 = row0 & 255;
    int b1 = row1 >> 8, s1 = row1 & 255;
#pragma unroll
    for (int n = 0; n < NTq; ++n) {
        u[(size_t)b0*(NTq*SCq) + n*SCq + s0*8 + cc] = acc0[n]*sc0;
        u[(size_t)b1*(NTq*SCq) + n*SCq + s1*8 + cc] = acc1[n]*sc1;
    }
}

// ---------------- Kernel 2: priors partials. part[ks][c][b][r][l] = sum_{k in half ks} u[b,r,k]*rw[c,r,k,l]
__global__ __launch_bounds__(256) void k2_priors(const float* __restrict__ u,
                                                 const float* __restrict__ rw,
                                                 float* __restrict__ part) {
    __shared__ float uS[64][33];
    __shared__ float wS[32][132];
    const int t = threadIdx.x;
    const int lt = blockIdx.x & 1;            // l-half
    const int ks = blockIdx.x >> 1;           // k-half
    const int r = blockIdx.y;
    const int c = blockIdx.z;
    const int tb = t >> 4, tl = t & 15;
    float acc[4][8];
#pragma unroll
    for (int i = 0; i < 4; ++i)
#pragma unroll
        for (int j = 0; j < 8; ++j) acc[i][j] = 0.f;

    const float* ub = u + (size_t)r * SCq + ks * 1024;                     // + b*NT*SC + k
    const float* wb = rw + ((size_t)(c*NTq + r) * SCq + ks*1024) * Sq + lt * 128;  // + k*S + l

    for (int kc = 0; kc < 1024; kc += 32) {
#pragma unroll
        for (int i = 0; i < 2; ++i) {
            int lin = t + i * 256;            // 0..511
            int bb = lin >> 3, k4 = (lin & 7) * 4;
            float4 v = *reinterpret_cast<const float4*>(&ub[(size_t)bb*(NTq*SCq) + kc + k4]);
            uS[bb][k4] = v.x; uS[bb][k4+1] = v.y; uS[bb][k4+2] = v.z; uS[bb][k4+3] = v.w;
        }
#pragma unroll
        for (int i = 0; i < 4; ++i) {
            int lin = t + i * 256;            // 0..1023
            int kk = lin >> 5, l4 = (lin & 31) * 4;
            float4 v = *reinterpret_cast<const float4*>(&wb[(size_t)(kc + kk)*Sq + l4]);
            *reinterpret_cast<float4*>(&wS[kk][l4]) = v;
        }
        __syncthreads();
#pragma unroll
        for (int kk = 0; kk < 32; ++kk) {
            float uv[4];
#pragma unroll
            for (int i = 0; i < 4; ++i) uv[i] = uS[tb + 16*i][kk];
            float4 w0 = *reinterpret_cast<const float4*>(&wS[kk][tl*4]);
            float4 w1 = *reinterpret_cast<const float4*>(&wS[kk][tl*4 + 64]);
#pragma unroll
            for (int i = 0; i < 4; ++i) {
                acc[i][0] = fmaf(uv[i], w0.x, acc[i][0]);
                acc[i][1] = fmaf(uv[i], w0.y, acc[i][1]);
                acc[i][2] = fmaf(uv[i], w0.z, acc[i][2]);
                acc[i][3] = fmaf(uv[i], w0.w, acc[i][3]);
                acc[i][4] = fmaf(uv[i], w1.x, acc[i][4]);
                acc[i][5] = fmaf(uv[i], w1.y, acc[i][5]);
                acc[i][6] = fmaf(uv[i], w1.z, acc[i][6]);
                acc[i][7] = fmaf(uv[i], w1.w, acc[i][7]);
            }
        }
        __syncthreads();
    }
#pragma unroll
    for (int i = 0; i < 4; ++i) {
        int bb = tb + 16*i;
        size_t base = ((((size_t)ks*CAPq + c)*Bq + bb)*NTq + r)*Sq + lt*128 + tl*4;
        *reinterpret_cast<float4*>(&part[base])      = make_float4(acc[i][0], acc[i][1], acc[i][2], acc[i][3]);
        *reinterpret_cast<float4*>(&part[base + 64]) = make_float4(acc[i][4], acc[i][5], acc[i][6], acc[i][7]);
    }
}

// ---------------- block reduce (256 threads)
__device__ __forceinline__ float block_reduce_sum(float v, float* red) {
#pragma unroll
    for (int o = 32; o > 0; o >>= 1) v += __shfl_xor(v, o, 64);
    int wid = threadIdx.x >> 6;
    if ((threadIdx.x & 63) == 0) red[wid] = v;
    __syncthreads();
    float r = red[0] + red[1] + red[2] + red[3];
    __syncthreads();
    return r;
}

// ---------------- Kernel 3: dynamic routing per (c,b). vote_out[c][b][l]
__global__ __launch_bounds__(256) void k3_route(const float* __restrict__ part,
                                                const int* __restrict__ task_p,
                                                float* __restrict__ vote_out) {
    __shared__ float pr[NTq][Sq];
    __shared__ float red[4];
    const int t = threadIdx.x;
    const int b = blockIdx.x & 63;
    const int c = blockIdx.x >> 6;
    const int task = *task_p;
    const size_t half = (size_t)CAPq * Bq * NTq * Sq;   // 1,310,720
    size_t base = ((size_t)(c*Bq + b) * NTq) * Sq;
#pragma unroll
    for (int r = 0; r < NTq; ++r)
        pr[r][t] = part[base + r*Sq + t] + part[half + base + r*Sq + t];
    __syncthreads();

    float logits[NTq];
#pragma unroll
    for (int r = 0; r < NTq; ++r) logits[r] = 0.f;
    float vote = 0.f;

    for (int it = 0; it < 3; ++it) {
        float m = -1e30f;
#pragma unroll
        for (int r = 0; r < NTq; ++r) if (r <= task) m = fmaxf(m, logits[r]);
        float p[NTq]; float s = 0.f;
#pragma unroll
        for (int r = 0; r < NTq; ++r) {
            p[r] = (r <= task) ? expf(logits[r] - m) : 0.f;
            s += p[r];
        }
        float inv = 1.f / s;
        vote = 0.f;
#pragma unroll
        for (int r = 0; r < NTq; ++r) vote = fmaf(p[r]*inv, pr[r][t], vote);
        if (it == 2) break;
        float sq = block_reduce_sum(vote*vote, red);
        float scale = (sq / (1.f + sq)) / sqrtf(sq);
        float outv = vote * scale;
#pragma unroll
        for (int r = 0; r < NTq; ++r) {
            float a = block_reduce_sum(pr[r][t] * outv, red);
            if (r <= task) logits[r] += a;
        }
    }
    vote_out[(size_t)(c*Bq + b)*Sq + t] = vote;
}

// ---------------- Kernel 4: h gather (flat reinterpret) + Linear(CAP->768)
__global__ __launch_bounds__(256) void k4_out(const float* __restrict__ vote, // [CAP][B][S] flat
                                              const float* __restrict__ lw,   // [768][8]
                                              const float* __restrict__ lb,   // [768]
                                              float* __restrict__ out) {      // [B,S,768]
    __shared__ float hS[8][8];
    const int t = threadIdx.x;
    if (t < 64) {
        int rr = t >> 3, cc = t & 7;
        size_t row = (size_t)blockIdx.x * 8 + rr;   // b'*256 + s'
        size_t flat = row * 8 + cc;                 // b'*2048 + s'*8 + c'
        int c = (int)(flat >> 14);                  // /16384
        int rem = (int)(flat & 16383);
        int bb = rem >> 8;
        int l = rem & 255;
        hS[rr][cc] = vote[(size_t)c*16384 + bb*256 + l];
    }
    float lwr[3][8];
    float lbr[3];
#pragma unroll
    for (int dd = 0; dd < 3; ++dd) {
        int d = t + dd*256;
        float4 a = *reinterpret_cast<const float4*>(&lw[(size_t)d*8]);
        float4 b2 = *reinterpret_cast<const float4*>(&lw[(size_t)d*8 + 4]);
        lwr[dd][0]=a.x; lwr[dd][1]=a.y; lwr[dd][2]=a.z; lwr[dd][3]=a.w;
        lwr[dd][4]=b2.x; lwr[dd][5]=b2.y; lwr[dd][6]=b2.z; lwr[dd][7]=b2.w;
        lbr[dd] = lb[d];
    }
    __syncthreads();
#pragma unroll
    for (int rr = 0; rr < 8; ++rr) {
        size_t row = (size_t)blockIdx.x * 8 + rr;
#pragma unroll
        for (int dd = 0; dd < 3; ++dd) {
            float acc = lbr[dd];
#pragma unroll
            for (int c = 0; c < 8; ++c) acc = fmaf(hS[rr][c], lwr[dd][c], acc);
            out[row*Dq + t + dd*256] = acc;
        }
    }
}

extern "C" void kernel_launch(void* const* d_in, const int* in_sizes, int n_in,
                              void* d_out, int out_size, void* d_ws, size_t ws_size,
                              hipStream_t stream) {
    const float* x    = (const float*)d_in[0];
    const int*   task = (const int*)d_in[1];
    const float* fc1w = (const float*)d_in[2];
    const float* fc1b = (const float*)d_in[3];
    const float* rw   = (const float*)d_in[4];
    const float* lw   = (const float*)d_in[5];
    const float* lb   = (const float*)d_in[6];
    float* out = (float*)d_out;

    float* u    = (float*)d_ws;                 // [64][10][2048]  = 1,310,720 f
    float* part = u + 1310720;                  // [2][8][64][10][256] = 2,621,440 f
    float* vote = part + 2*1310720;             // [8][64][256]    = 131,072 f

    k1_sem<<<256, 256, 0, stream>>>(x, fc1w, fc1b, u);
    dim3 g2(4, NTq, CAPq);
    k2_priors<<<g2, 256, 0, stream>>>(u, rw, part);
    k3_route<<<512, 256, 0, stream>>>(part, task, vote);
    k4_out<<<2048, 256, 0, stream>>>(vote, lw, lb, out);
}

// Round 3
// 242.740 us; speedup vs baseline: 1.0100x; 1.0100x over previous
//
#include <hip/hip_runtime.h>

#define Bq 64
#define Sq 256
#define Dq 768
#define CAPq 8
#define NTq 10
#define SCq 2048   // S*CAP

// ---------------- Kernel 1: sem[b,s,c,n] = x[b,s,:]·fc1_w[n,c,:] + b, squash over n,
// write u[b][n][s*8+c]  (u is [B][NT][S*CAP])
__global__ __launch_bounds__(256) void k1_sem(const float* __restrict__ x,
                                              const float* __restrict__ fc1w,
                                              const float* __restrict__ fc1b,
                                              float* __restrict__ u) {
    __shared__ float xs[64][33];
    __shared__ float ws[80][33];
    const int t = threadIdx.x;
    const int R0 = blockIdx.x * 64;           // global row = b*256 + s
    const int rp = t >> 3;                    // 0..31 -> rows 2rp, 2rp+1
    const int cc = t & 7;                     // capsule
    float acc0[NTq], acc1[NTq];
#pragma unroll
    for (int n = 0; n < NTq; ++n) { acc0[n] = 0.f; acc1[n] = 0.f; }

    for (int kc = 0; kc < Dq; kc += 32) {
#pragma unroll
        for (int i = 0; i < 2; ++i) {
            int lin = t + i * 256;            // 0..511
            int r = lin >> 3, k4 = (lin & 7) * 4;
            float4 v = *reinterpret_cast<const float4*>(&x[(size_t)(R0 + r) * Dq + kc + k4]);
            xs[r][k4] = v.x; xs[r][k4+1] = v.y; xs[r][k4+2] = v.z; xs[r][k4+3] = v.w;
        }
#pragma unroll
        for (int i = 0; i < 3; ++i) {
            int lin = t + i * 256;
            if (lin < 640) {                  // 80*32/4
                int o = lin >> 3, k4 = (lin & 7) * 4;
                float4 v = *reinterpret_cast<const float4*>(&fc1w[(size_t)o * Dq + kc + k4]);
                ws[o][k4] = v.x; ws[o][k4+1] = v.y; ws[o][k4+2] = v.z; ws[o][k4+3] = v.w;
            }
        }
        __syncthreads();
#pragma unroll
        for (int k = 0; k < 32; ++k) {
            float x0 = xs[2*rp][k], x1 = xs[2*rp+1][k];
#pragma unroll
            for (int n = 0; n < NTq; ++n) {
                float wv = ws[n*8 + cc][k];
                acc0[n] = fmaf(x0, wv, acc0[n]);
                acc1[n] = fmaf(x1, wv, acc1[n]);
            }
        }
        __syncthreads();
    }
    float sq0 = 0.f, sq1 = 0.f;
#pragma unroll
    for (int n = 0; n < NTq; ++n) {
        float bias = fc1b[n*8 + cc];
        acc0[n] += bias; acc1[n] += bias;
        sq0 = fmaf(acc0[n], acc0[n], sq0);
        sq1 = fmaf(acc1[n], acc1[n], sq1);
    }
    float sc0 = (sq0 / (1.f + sq0)) / sqrtf(sq0);
    float sc1 = (sq1 / (1.f + sq1)) / sqrtf(sq1);
    int row0 = R0 + 2*rp, row1 = row0 + 1;
    int b0 = row0 >> 8, s0 = row0 & 255;
    int b1 = row1 >> 8, s1 = row1 & 255;
#pragma unroll
    for (int n = 0; n < NTq; ++n) {
        u[(size_t)b0*(NTq*SCq) + n*SCq + s0*8 + cc] = acc0[n]*sc0;
        u[(size_t)b1*(NTq*SCq) + n*SCq + s1*8 + cc] = acc1[n]*sc1;
    }
}

// ---------------- Kernel 2: priors partials. part[ks][c][b][r][l] = sum_{k in half ks} u[b,r,k]*rw[c,r,k,l]
__global__ __launch_bounds__(256) void k2_priors(const float* __restrict__ u,
                                                 const float* __restrict__ rw,
                                                 float* __restrict__ part) {
    __shared__ float uS[64][33];
    __shared__ float wS[32][132];
    const int t = threadIdx.x;
    const int lt = blockIdx.x & 1;            // l-half
    const int ks = blockIdx.x >> 1;           // k-half
    const int r = blockIdx.y;
    const int c = blockIdx.z;
    const int tb = t >> 4, tl = t & 15;
    float acc[4][8];
#pragma unroll
    for (int i = 0; i < 4; ++i)
#pragma unroll
        for (int j = 0; j < 8; ++j) acc[i][j] = 0.f;

    const float* ub = u + (size_t)r * SCq + ks * 1024;                     // + b*NT*SC + k
    const float* wb = rw + ((size_t)(c*NTq + r) * SCq + ks*1024) * Sq + lt * 128;  // + k*S + l

    for (int kc = 0; kc < 1024; kc += 32) {
#pragma unroll
        for (int i = 0; i < 2; ++i) {
            int lin = t + i * 256;            // 0..511
            int bb = lin >> 3, k4 = (lin & 7) * 4;
            float4 v = *reinterpret_cast<const float4*>(&ub[(size_t)bb*(NTq*SCq) + kc + k4]);
            uS[bb][k4] = v.x; uS[bb][k4+1] = v.y; uS[bb][k4+2] = v.z; uS[bb][k4+3] = v.w;
        }
#pragma unroll
        for (int i = 0; i < 4; ++i) {
            int lin = t + i * 256;            // 0..1023
            int kk = lin >> 5, l4 = (lin & 31) * 4;
            float4 v = *reinterpret_cast<const float4*>(&wb[(size_t)(kc + kk)*Sq + l4]);
            *reinterpret_cast<float4*>(&wS[kk][l4]) = v;
        }
        __syncthreads();
#pragma unroll
        for (int kk = 0; kk < 32; ++kk) {
            float uv[4];
#pragma unroll
            for (int i = 0; i < 4; ++i) uv[i] = uS[tb + 16*i][kk];
            float4 w0 = *reinterpret_cast<const float4*>(&wS[kk][tl*4]);
            float4 w1 = *reinterpret_cast<const float4*>(&wS[kk][tl*4 + 64]);
#pragma unroll
            for (int i = 0; i < 4; ++i) {
                acc[i][0] = fmaf(uv[i], w0.x, acc[i][0]);
                acc[i][1] = fmaf(uv[i], w0.y, acc[i][1]);
                acc[i][2] = fmaf(uv[i], w0.z, acc[i][2]);
                acc[i][3] = fmaf(uv[i], w0.w, acc[i][3]);
                acc[i][4] = fmaf(uv[i], w1.x, acc[i][4]);
                acc[i][5] = fmaf(uv[i], w1.y, acc[i][5]);
                acc[i][6] = fmaf(uv[i], w1.z, acc[i][6]);
                acc[i][7] = fmaf(uv[i], w1.w, acc[i][7]);
            }
        }
        __syncthreads();
    }
#pragma unroll
    for (int i = 0; i < 4; ++i) {
        int bb = tb + 16*i;
        size_t base = ((((size_t)ks*CAPq + c)*Bq + bb)*NTq + r)*Sq + lt*128 + tl*4;
        *reinterpret_cast<float4*>(&part[base])      = make_float4(acc[i][0], acc[i][1], acc[i][2], acc[i][3]);
        *reinterpret_cast<float4*>(&part[base + 64]) = make_float4(acc[i][4], acc[i][5], acc[i][6], acc[i][7]);
    }
}

// ---------------- block reduce (256 threads)
__device__ __forceinline__ float block_reduce_sum(float v, float* red) {
#pragma unroll
    for (int o = 32; o > 0; o >>= 1) v += __shfl_xor(v, o, 64);
    int wid = threadIdx.x >> 6;
    if ((threadIdx.x & 63) == 0) red[wid] = v;
    __syncthreads();
    float r = red[0] + red[1] + red[2] + red[3];
    __syncthreads();
    return r;
}

// ---------------- Kernel 3: dynamic routing per (c,b). vote_out[c][b][l]
__global__ __launch_bounds__(256) void k3_route(const float* __restrict__ part,
                                                const int* __restrict__ task_p,
                                                float* __restrict__ vote_out) {
    __shared__ float pr[NTq][Sq];
    __shared__ float red[4];
    const int t = threadIdx.x;
    const int b = blockIdx.x & 63;
    const int c = blockIdx.x >> 6;
    const int task = *task_p;
    const size_t half = (size_t)CAPq * Bq * NTq * Sq;   // 1,310,720
    size_t base = ((size_t)(c*Bq + b) * NTq) * Sq;
#pragma unroll
    for (int r = 0; r < NTq; ++r)
        pr[r][t] = part[base + r*Sq + t] + part[half + base + r*Sq + t];
    __syncthreads();

    float logits[NTq];
#pragma unroll
    for (int r = 0; r < NTq; ++r) logits[r] = 0.f;
    float vote = 0.f;

    for (int it = 0; it < 3; ++it) {
        float m = -1e30f;
#pragma unroll
        for (int r = 0; r < NTq; ++r) if (r <= task) m = fmaxf(m, logits[r]);
        float p[NTq]; float s = 0.f;
#pragma unroll
        for (int r = 0; r < NTq; ++r) {
            p[r] = (r <= task) ? expf(logits[r] - m) : 0.f;
            s += p[r];
        }
        float inv = 1.f / s;
        vote = 0.f;
#pragma unroll
        for (int r = 0; r < NTq; ++r) vote = fmaf(p[r]*inv, pr[r][t], vote);
        if (it == 2) break;
        float sq = block_reduce_sum(vote*vote, red);
        float scale = (sq / (1.f + sq)) / sqrtf(sq);
        float outv = vote * scale;
#pragma unroll
        for (int r = 0; r < NTq; ++r) {
            float a = block_reduce_sum(pr[r][t] * outv, red);
            if (r <= task) logits[r] += a;
        }
    }
    vote_out[(size_t)(c*Bq + b)*Sq + t] = vote;
}

// ---------------- Kernel 4: h gather (flat reinterpret) + Linear(CAP->768)
__global__ __launch_bounds__(256) void k4_out(const float* __restrict__ vote, // [CAP][B][S] flat
                                              const float* __restrict__ lw,   // [768][8]
                                              const float* __restrict__ lb,   // [768]
                                              float* __restrict__ out) {      // [B,S,768]
    __shared__ float hS[8][8];
    const int t = threadIdx.x;
    if (t < 64) {
        int rr = t >> 3, cc = t & 7;
        size_t row = (size_t)blockIdx.x * 8 + rr;   // b'*256 + s'
        size_t flat = row * 8 + cc;                 // b'*2048 + s'*8 + c'
        int c = (int)(flat >> 14);                  // /16384
        int rem = (int)(flat & 16383);
        int bb = rem >> 8;
        int l = rem & 255;
        hS[rr][cc] = vote[(size_t)c*16384 + bb*256 + l];
    }
    float lwr[3][8];
    float lbr[3];
#pragma unroll
    for (int dd = 0; dd < 3; ++dd) {
        int d = t + dd*256;
        float4 a = *reinterpret_cast<const float4*>(&lw[(size_t)d*8]);
        float4 b2 = *reinterpret_cast<const float4*>(&lw[(size_t)d*8 + 4]);
        lwr[dd][0]=a.x; lwr[dd][1]=a.y; lwr[dd][2]=a.z; lwr[dd][3]=a.w;
        lwr[dd][4]=b2.x; lwr[dd][5]=b2.y; lwr[dd][6]=b2.z; lwr[dd][7]=b2.w;
        lbr[dd] = lb[d];
    }
    __syncthreads();
#pragma unroll
    for (int rr = 0; rr < 8; ++rr) {
        size_t row = (size_t)blockIdx.x * 8 + rr;
#pragma unroll
        for (int dd = 0; dd < 3; ++dd) {
            float acc = lbr[dd];
#pragma unroll
            for (int c = 0; c < 8; ++c) acc = fmaf(hS[rr][c], lwr[dd][c], acc);
            out[row*Dq + t + dd*256] = acc;
        }
    }
}

extern "C" void kernel_launch(void* const* d_in, const int* in_sizes, int n_in,
                              void* d_out, int out_size, void* d_ws, size_t ws_size,
                              hipStream_t stream) {
    const float* x    = (const float*)d_in[0];
    const int*   task = (const int*)d_in[1];
    const float* fc1w = (const float*)d_in[2];
    const float* fc1b = (const float*)d_in[3];
    const float* rw   = (const float*)d_in[4];
    const float* lw   = (const float*)d_in[5];
    const float* lb   = (const float*)d_in[6];
    float* out = (float*)d_out;

    float* u    = (float*)d_ws;                 // [64][10][2048]  = 1,310,720 f
    float* part = u + 1310720;                  // [2][8][64][10][256] = 2,621,440 f
    float* vote = part + 2*1310720;             // [8][64][256]    = 131,072 f

    k1_sem<<<256, 256, 0, stream>>>(x, fc1w, fc1b, u);
    dim3 g2(4, NTq, CAPq);
    k2_priors<<<g2, 256, 0, stream>>>(u, rw, part);
    k3_route<<<512, 256, 0, stream>>>(part, task, vote);
    k4_out<<<2048, 256, 0, stream>>>(vote, lw, lb, out);
}